// Round 11
// baseline (133.997 us; speedup 1.0000x reference)
//
#include <hip/hip_runtime.h>

#define WF 512
#define HF 256
#define CF 64
#define NDTOT 65
#define DP 72            // padded d-stride in ws (f16 elements), 144 B rows

static constexpr size_t CH  = (size_t)HF * WF;
static constexpr size_t WH  = (size_t)HF * WF;
static constexpr float  INV = 1.0f / 576.0f;

typedef _Float16 f16;
typedef _Float16 f16x4 __attribute__((ext_vector_type(4)));
typedef _Float16 f16x8 __attribute__((ext_vector_type(8)));
typedef float    f32x4 __attribute__((ext_vector_type(4)));

#if __has_builtin(__builtin_amdgcn_mfma_f32_16x16x16f16)
#define MFMA16(A, B, C) __builtin_amdgcn_mfma_f32_16x16x16f16((A), (B), (C), 0, 0, 0)
#define FRAG_T f16x4
__device__ __forceinline__ f16x4 mkfrag(f16 a, f16 b, f16 c, f16 d) {
    f16x4 r; r[0] = a; r[1] = b; r[2] = c; r[3] = d; return r;
}
#else
// Fallback: proven 16x16x32 with upper half of K zeroed on BOTH operands
// (any injective k->channel assignment works if A and B agree; absent k = 0).
#define MFMA16(A, B, C) __builtin_amdgcn_mfma_f32_16x16x32_f16((A), (B), (C), 0, 0, 0)
#define FRAG_T f16x8
__device__ __forceinline__ f16x8 mkfrag(f16 a, f16 b, f16 c, f16 d) {
    f16x8 r; r[0] = a; r[1] = b; r[2] = c; r[3] = d;
    r[4] = (f16)0.f; r[5] = (f16)0.f; r[6] = (f16)0.f; r[7] = (f16)0.f; return r;
}
#endif

// ---------------------------------------------------------------------------
// k1 (R11): banded Gram via MFMA, fp16 hi/lo (hh+hl+lh), WAVE-AUTONOMOUS.
// Each wave owns one (b, y, 32-col strip) tile: NO barriers, NO DMA.
// K-loop: 4 iters of 16 channels. Per iter: 32 coalesced scalar f32 global
// loads (prefetched one iter ahead), ds_write_b128 into a k-contiguous,
// quad-XOR-swizzled wave-private 8 KB LDS region, fragments via single
// ds_read_b128 each, cvt f16 hi/lo, 30 MFMAs (10 band acc tiles).
// Band mapping d = 16p + n - m and epilogue validated R5-R9.
// ---------------------------------------------------------------------------
__global__ __launch_bounds__(256, 4)
void corr_gram(const float* __restrict__ x0, const float* __restrict__ x1,
               f16* __restrict__ ws) {
    // XCD swizzle: consecutive tiles of one row on one XCD.
    const int f = blockIdx.x;              // [0, 4096)
    const int tid = (f & 7) * 512 + (f >> 3);
    const int b = tid >> 10;
    const int y = (tid >> 2) & 255;
    const int sg = tid & 3;

    const int t = threadIdx.x;
    const int l = t & 63;
    const int w = t >> 6;
    const int xs = (sg * 4 + w) * 32;      // wave's 32-col strip
    const int jb = xs - 32;

    const int n  = l & 15;                 // fragment row/col
    const int kq = l >> 4;                 // fragment k-quad
    const int sn = (n & 3) ^ (n >> 2);     // read-side XOR (col = 16xt+n -> same sn)

    __shared__ float lds[8192];            // 32 KB; 2048 floats per wave (private)
    float* base = lds + w * 2048;          // A: [0,512) = [32col][16ch]; B: [512,2048) = [96col][16ch]

    const float* x0r = x0 + (size_t)b * CF * CH + (size_t)y * WF;
    const float* x1r = x1 + (size_t)b * CF * CH + (size_t)y * WF;

    // ---- staging units (precomputed, lane-constant) ----
    // A: 2 units: col c0 = l&31, ch-quads qa, qa+2
    const int c0 = l & 31, qa = l >> 5;
    const int sA = (c0 & 3) ^ ((c0 >> 2) & 3);
    int aoff[2], awad[2];
    aoff[0] = (4 * qa) * (int)CH + xs + c0;
    aoff[1] = (4 * (qa + 2)) * (int)CH + xs + c0;
    awad[0] = c0 * 16 + 4 * (qa ^ sA);
    awad[1] = c0 * 16 + 4 * ((qa + 2) ^ sA);
    // B: 6 units: v = 64u+l -> quad q = v/96, col cb = v%96 (coalesced runs)
    int boff[6], bwad[6];
#pragma unroll
    for (int u = 0; u < 6; ++u) {
        const int v = u * 64 + l;
        const int q = v / 96;
        const int cb = v - 96 * q;
        int jg = jb + cb;
        jg = jg < 0 ? 0 : (jg > 511 ? 511 : jg);   // clamp; zeroed at consume
        boff[u] = (4 * q) * (int)CH + jg;
        bwad[u] = 512 + cb * 16 + 4 * (q ^ ((cb & 3) ^ ((cb >> 2) & 3)));
    }

    // ---- fragment read addresses (b128 each) ----
    int ard[2], brd[6];
#pragma unroll
    for (int xt = 0; xt < 2; ++xt) ard[xt] = (16 * xt + n) * 16 + 4 * (kq ^ sn);
#pragma unroll
    for (int jt = 0; jt < 6; ++jt) brd[jt] = 512 + (16 * jt + n) * 16 + 4 * (kq ^ sn);
    bool okj[6];
#pragma unroll
    for (int jt = 0; jt < 6; ++jt) okj[jt] = (unsigned)(jb + 16 * jt + n) < (unsigned)WF;

    f32x4 acc[10];
#pragma unroll
    for (int i = 0; i < 10; ++i) acc[i] = (f32x4)0.0f;

    float ra[8], rb[24];
#define LOADK(kk) do { const int kb = 16 * (kk) * (int)CH; \
    _Pragma("unroll") for (int j = 0; j < 2; ++j) \
    _Pragma("unroll") for (int i = 0; i < 4; ++i) ra[4*j+i] = x0r[aoff[j] + kb + i * (int)CH]; \
    _Pragma("unroll") for (int u = 0; u < 6; ++u) \
    _Pragma("unroll") for (int i = 0; i < 4; ++i) rb[4*u+i] = x1r[boff[u] + kb + i * (int)CH]; \
    } while (0)

#define TRIPLE(ai, AH, AL) do { \
    acc[ai] = MFMA16(AH, bh, acc[ai]); \
    acc[ai] = MFMA16(AH, bl, acc[ai]); \
    acc[ai] = MFMA16(AL, bh, acc[ai]); } while (0)

    LOADK(0);

#pragma unroll 1
    for (int kk = 0; kk < 4; ++kk) {
        // ---- stage to wave-private LDS (k-contiguous, swizzled) ----
#pragma unroll
        for (int j = 0; j < 2; ++j)
            *(float4*)&base[awad[j]] = make_float4(ra[4*j], ra[4*j+1], ra[4*j+2], ra[4*j+3]);
#pragma unroll
        for (int u = 0; u < 6; ++u)
            *(float4*)&base[bwad[u]] = make_float4(rb[4*u], rb[4*u+1], rb[4*u+2], rb[4*u+3]);

        if (kk < 3) LOADK(kk + 1);         // prefetch next K-step (T14)

        // ---- A fragments ----
        FRAG_T ah[2], al[2];
#pragma unroll
        for (int xt = 0; xt < 2; ++xt) {
            const float4 fa = *(const float4*)&base[ard[xt]];
            const float tmp[4] = {fa.x, fa.y, fa.z, fa.w};
            f16 h0 = (f16)tmp[0], h1 = (f16)tmp[1], h2 = (f16)tmp[2], h3 = (f16)tmp[3];
            ah[xt] = mkfrag(h0, h1, h2, h3);
            al[xt] = mkfrag((f16)(tmp[0] - (float)h0), (f16)(tmp[1] - (float)h1),
                            (f16)(tmp[2] - (float)h2), (f16)(tmp[3] - (float)h3));
        }
        // ---- B fragments + MFMA ----
#pragma unroll
        for (int jt = 0; jt < 6; ++jt) {
            const float4 fb = *(const float4*)&base[brd[jt]];
            float tmp[4] = {fb.x, fb.y, fb.z, fb.w};
#pragma unroll
            for (int i = 0; i < 4; ++i) tmp[i] = okj[jt] ? tmp[i] : 0.f;
            f16 h0 = (f16)tmp[0], h1 = (f16)tmp[1], h2 = (f16)tmp[2], h3 = (f16)tmp[3];
            const FRAG_T bh = mkfrag(h0, h1, h2, h3);
            const FRAG_T bl = mkfrag((f16)(tmp[0] - (float)h0), (f16)(tmp[1] - (float)h1),
                                     (f16)(tmp[2] - (float)h2), (f16)(tmp[3] - (float)h3));
            if (jt < 5)  TRIPLE(jt, ah[0], al[0]);
            if (jt >= 1) TRIPLE(4 + jt, ah[1], al[1]);
        }
    }
#undef TRIPLE
#undef LOADK

    // ---- epilogue (wave-private): scatter band to LDS, coalesced stores ----
    // eb: [32 col][72 d] f16 = 4608 B inside the wave's region.
    f16* eb = (f16*)base;
#pragma unroll
    for (int xt = 0; xt < 2; ++xt) {
#pragma unroll
        for (int p = 0; p < 5; ++p) {
            const int i = xt * 5 + p;
#pragma unroll
            for (int q = 0; q < 4; ++q) {
                const int m = kq * 4 + q;
                const int xl = xt * 16 + m;
                const int d = 16 * p + n - m;
                if ((unsigned)d < (unsigned)NDTOT)
                    eb[xl * DP + d] = (f16)acc[i][q];
            }
        }
    }
    // zero pad columns d=65..71 (32 x 7 = 224 entries)
#pragma unroll
    for (int i = 0; i < 4; ++i) {
        const int idx = l + 64 * i;
        if (idx < 224) {
            const int xl = idx / 7;
            eb[xl * DP + NDTOT + (idx - 7 * xl)] = (f16)0.f;
        }
    }
    // coalesced store: 32*72 f16 = 4608 B = 288 x 16B chunks (contiguous in ws)
    uint4* dst = (uint4*)(ws + ((size_t)(b * HF + y) * WF + xs) * DP);
    const uint4* src = (const uint4*)eb;
#pragma unroll
    for (int i = 0; i < 5; ++i) {
        const int idx = l + 64 * i;
        if (idx < 288) dst[idx] = src[idx];
    }
}

// ---------------------------------------------------------------------------
// k2: 3x3 box-sum over ws + scale: out[b,d,y,x] = INV * sum_{3x3} ws[y+dy][x+dx][d]
// grid (16 x-tiles of 32, 32 y-tiles of 8, b); 256 thr.
// ---------------------------------------------------------------------------
__global__ __launch_bounds__(256)
void corr_box(const f16* __restrict__ ws, float* __restrict__ out) {
    const int xt = blockIdx.x;
    const int yt = blockIdx.y;
    const int b = blockIdx.z;
    const int t = threadIdx.x;
    const int x0b = xt * 32, y0 = yt * 8;

    __shared__ f16 S[10 * 34][DP];     // 48.96 KB

    for (int u = 0; u < 10; ++u) {
        const int yy = y0 - 1 + u;
        const bool yok = (unsigned)yy < (unsigned)HF;
        const f16* src = ws + ((size_t)(b * HF + yy) * WF + (x0b - 1)) * DP;
#pragma unroll
        for (int sub = 0; sub < 2; ++sub) {
            const int idx = sub * 256 + t;
            if (idx < 306) {
                const int v = idx / 9, dg = idx - v * 9;
                const int xx = x0b - 1 + v;
                f16x8 val;
#pragma unroll
                for (int jj = 0; jj < 8; ++jj) val[jj] = (f16)0.f;
                if (yok && (unsigned)xx < (unsigned)WF)
                    val = *(const f16x8*)(src + (size_t)v * DP + dg * 8);
                *(f16x8*)&S[u * 34 + v][dg * 8] = val;
            }
        }
    }
    __syncthreads();

    const int ly = t >> 5, lx = t & 31;
    const int yg = y0 + ly, xg = x0b + lx;
    float* o0 = out + (size_t)b * NDTOT * WH + (size_t)yg * WF + xg;

#pragma unroll 1
    for (int dg = 0; dg < 9; ++dg) {
        f16x8 s;
#pragma unroll
        for (int jj = 0; jj < 8; ++jj) s[jj] = (f16)0.f;
#pragma unroll
        for (int du = 0; du < 3; ++du)
#pragma unroll
            for (int dv = 0; dv < 3; ++dv)
                s += *(const f16x8*)&S[(ly + du) * 34 + (lx + dv)][dg * 8];
#pragma unroll
        for (int jj = 0; jj < 8; ++jj) {
            const int d = dg * 8 + jj;
            if (d < NDTOT) o0[(size_t)d * WH] = (float)s[jj] * INV;
        }
    }
}

// ---------------------------------------------------------------------------
// Emergency fallback (tiny ws): direct computation, slow but correct.
// ---------------------------------------------------------------------------
__global__ void corr_naive(const float* __restrict__ x0, const float* __restrict__ x1,
                           float* __restrict__ out) {
    const size_t total = (size_t)4 * NDTOT * WH;
    size_t idx = (size_t)blockIdx.x * blockDim.x + threadIdx.x;
    if (idx >= total) return;
    const int j = (int)(idx % WF);
    const int i = (int)((idx / WF) % HF);
    const int d = (int)((idx / WH) % NDTOT);
    const int b = (int)(idx / ((size_t)NDTOT * WH));
    const int disp = d - 32;
    float s = 0.f;
    for (int u = i - 1; u <= i + 1; ++u) {
        if (u < 0 || u >= HF) continue;
        for (int v = j - 1; v <= j + 1; ++v) {
            if (v < 0 || v >= WF) continue;
            const int v1c = v + disp;
            if (v1c < 0 || v1c >= WF) continue;
            const float* p0 = x0 + (size_t)b * CF * CH + (size_t)u * WF + v;
            const float* p1 = x1 + (size_t)b * CF * CH + (size_t)u * WF + v1c;
            for (int c = 0; c < CF; ++c)
                s += p0[(size_t)c * CH] * p1[(size_t)c * CH];
        }
    }
    out[idx] = s * INV;
}

// ---------------------------------------------------------------------------
extern "C" void kernel_launch(void* const* d_in, const int* in_sizes, int n_in,
                              void* d_out, int out_size, void* d_ws, size_t ws_size,
                              hipStream_t stream) {
    const float* x0 = (const float*)d_in[0];
    const float* x1 = (const float*)d_in[1];
    float* out = (float*)d_out;

    const size_t wsNeed = (size_t)4 * HF * WF * DP * sizeof(f16);  // 75.5 MB

    if (ws_size >= wsNeed) {
        f16* ws = (f16*)d_ws;
        corr_gram<<<dim3(4096), dim3(256), 0, stream>>>(x0, x1, ws);
        corr_box<<<dim3(16, 32, 4), dim3(256), 0, stream>>>(ws, out);
    } else {
        const size_t total = (size_t)4 * NDTOT * WH;
        const int blocks = (int)((total + 255) / 256);
        corr_naive<<<dim3(blocks), dim3(256), 0, stream>>>(x0, x1, out);
    }
}

// Round 12
// 127.999 us; speedup vs baseline: 1.0469x; 1.0469x over previous
//
#include <hip/hip_runtime.h>

#define WF 512
#define HF 256
#define CF 64
#define NDTOT 65
#define DP 72            // padded d-stride in ws (f16 elements), 144 B rows

static constexpr size_t CH  = (size_t)HF * WF;
static constexpr size_t WH  = (size_t)HF * WF;
static constexpr float  INV = 1.0f / 576.0f;

typedef _Float16 f16;
typedef _Float16 f16x4 __attribute__((ext_vector_type(4)));
typedef _Float16 f16x8 __attribute__((ext_vector_type(8)));
typedef float    f32x4 __attribute__((ext_vector_type(4)));

#if __has_builtin(__builtin_amdgcn_mfma_f32_16x16x16f16)
#define MFMA16(A, B, C) __builtin_amdgcn_mfma_f32_16x16x16f16((A), (B), (C), 0, 0, 0)
#define FRAG_T f16x4
__device__ __forceinline__ f16x4 mkfrag(f16 a, f16 b, f16 c, f16 d) {
    f16x4 r; r[0] = a; r[1] = b; r[2] = c; r[3] = d; return r;
}
#else
// Fallback: 16x16x32 with upper half of K zeroed on BOTH operands.
#define MFMA16(A, B, C) __builtin_amdgcn_mfma_f32_16x16x32_f16((A), (B), (C), 0, 0, 0)
#define FRAG_T f16x8
__device__ __forceinline__ f16x8 mkfrag(f16 a, f16 b, f16 c, f16 d) {
    f16x8 r; r[0] = a; r[1] = b; r[2] = c; r[3] = d;
    r[4] = (f16)0.f; r[5] = (f16)0.f; r[6] = (f16)0.f; r[7] = (f16)0.f; return r;
}
#endif

// Inline-asm scalar load: SGPR-pair base + 32-bit per-lane byte offset.
// "=v" outputs of a 32-load batch are simultaneously live -> allocator MUST
// keep the batch in registers; asm volatile keeps issue order contiguous.
#define GLOADF(dst, ptr, offbytes) \
    asm volatile("global_load_dword %0, %1, %2" \
                 : "=v"(dst) : "v"(offbytes), "s"(ptr))

// ---------------------------------------------------------------------------
// k1 (R12): banded Gram via MFMA, fp16 hi/lo (hh+hl+lh), WAVE-AUTONOMOUS,
// with FORCED 32-deep load batching (inline-asm global_load_dword).
// Each wave owns one (b, y, 32-col strip): no barriers, no DMA.
// K-loop: 4 iters x 16 ch. Per iter: wait vmcnt(0) (prev batch), stage 8 x
// ds_write_b128 into k-contiguous quad-XOR LDS, issue next 32-load batch,
// frags via single ds_read_b128 each, cvt hi/lo, 30 MFMAs.
// Band mapping d=16p+n-m and epilogue validated R5-R11.
// ---------------------------------------------------------------------------
__global__ __launch_bounds__(256) __attribute__((amdgpu_waves_per_eu(2, 4)))
void corr_gram(const float* __restrict__ x0, const float* __restrict__ x1,
               f16* __restrict__ ws) {
    // XCD swizzle: consecutive tiles of one row on one XCD.
    const int f = blockIdx.x;              // [0, 4096)
    const int tid = (f & 7) * 512 + (f >> 3);
    const int b = tid >> 10;
    const int y = (tid >> 2) & 255;
    const int sg = tid & 3;

    const int t = threadIdx.x;
    const int l = t & 63;
    const int w = t >> 6;
    const int xs = (sg * 4 + w) * 32;      // wave's 32-col strip
    const int jb = xs - 32;

    const int n  = l & 15;                 // fragment row/col
    const int kq = l >> 4;                 // fragment k-quad
    const int sn = (n & 3) ^ (n >> 2);     // read-side XOR

    __shared__ float lds[8192];            // 32 KB; 2048 floats per wave
    float* base = lds + w * 2048;          // A: [0,512); B: [512,2048)

    const float* x0r = x0 + (size_t)b * CF * CH + (size_t)y * WF;
    const float* x1r = x1 + (size_t)b * CF * CH + (size_t)y * WF;

    // ---- staging units (lane-constant) ----
    const int c0 = l & 31, qa = l >> 5;
    const int sA = (c0 & 3) ^ ((c0 >> 2) & 3);
    int aoff[2], awad[2];
    aoff[0] = (4 * qa) * (int)CH + xs + c0;
    aoff[1] = (4 * (qa + 2)) * (int)CH + xs + c0;
    awad[0] = c0 * 16 + 4 * (qa ^ sA);
    awad[1] = c0 * 16 + 4 * ((qa + 2) ^ sA);
    int boff[6], bwad[6];
#pragma unroll
    for (int u = 0; u < 6; ++u) {
        const int v = u * 64 + l;
        const int q = v / 96;
        const int cb = v - 96 * q;
        int jg = jb + cb;
        jg = jg < 0 ? 0 : (jg > 511 ? 511 : jg);   // clamp; zeroed at consume
        boff[u] = (4 * q) * (int)CH + jg;
        bwad[u] = 512 + cb * 16 + 4 * (q ^ ((cb & 3) ^ ((cb >> 2) & 3)));
    }

    // ---- fragment read addresses (b128 each) ----
    int ard[2], brd[6];
#pragma unroll
    for (int xt = 0; xt < 2; ++xt) ard[xt] = (16 * xt + n) * 16 + 4 * (kq ^ sn);
#pragma unroll
    for (int jt = 0; jt < 6; ++jt) brd[jt] = 512 + (16 * jt + n) * 16 + 4 * (kq ^ sn);
    bool okj[6];
#pragma unroll
    for (int jt = 0; jt < 6; ++jt) okj[jt] = (unsigned)(jb + 16 * jt + n) < (unsigned)WF;

    f32x4 acc[10];
#pragma unroll
    for (int i = 0; i < 10; ++i) acc[i] = (f32x4)0.0f;

    float ra[8], rb[24];

#define LOADK(kk) do { \
    const int kb4 = 4 * (16 * (kk) * (int)CH); \
    _Pragma("unroll") for (int j = 0; j < 2; ++j) \
    _Pragma("unroll") for (int i = 0; i < 4; ++i) \
        GLOADF(ra[4*j+i], x0r, 4 * aoff[j] + kb4 + 4 * i * (int)CH); \
    _Pragma("unroll") for (int u = 0; u < 6; ++u) \
    _Pragma("unroll") for (int i = 0; i < 4; ++i) \
        GLOADF(rb[4*u+i], x1r, 4 * boff[u] + kb4 + 4 * i * (int)CH); \
    __builtin_amdgcn_sched_barrier(0); \
} while (0)

#define TRIPLE(ai, AH, AL) do { \
    acc[ai] = MFMA16(AH, bh, acc[ai]); \
    acc[ai] = MFMA16(AH, bl, acc[ai]); \
    acc[ai] = MFMA16(AL, bh, acc[ai]); } while (0)

    LOADK(0);

#pragma unroll 1
    for (int kk = 0; kk < 4; ++kk) {
        // ---- wait for the batch issued one full compute-phase ago ----
        asm volatile("s_waitcnt vmcnt(0)" ::: "memory");
        __builtin_amdgcn_sched_barrier(0);

        // ---- stage to wave-private LDS (k-contiguous, swizzled) ----
#pragma unroll
        for (int j = 0; j < 2; ++j)
            *(float4*)&base[awad[j]] = make_float4(ra[4*j], ra[4*j+1], ra[4*j+2], ra[4*j+3]);
#pragma unroll
        for (int u = 0; u < 6; ++u)
            *(float4*)&base[bwad[u]] = make_float4(rb[4*u], rb[4*u+1], rb[4*u+2], rb[4*u+3]);

        if (kk < 3) LOADK(kk + 1);         // issue next batch early (T14)

        // ---- A fragments ----
        FRAG_T ah[2], al[2];
#pragma unroll
        for (int xt = 0; xt < 2; ++xt) {
            const float4 fa = *(const float4*)&base[ard[xt]];
            const float tmp[4] = {fa.x, fa.y, fa.z, fa.w};
            f16 h0 = (f16)tmp[0], h1 = (f16)tmp[1], h2 = (f16)tmp[2], h3 = (f16)tmp[3];
            ah[xt] = mkfrag(h0, h1, h2, h3);
            al[xt] = mkfrag((f16)(tmp[0] - (float)h0), (f16)(tmp[1] - (float)h1),
                            (f16)(tmp[2] - (float)h2), (f16)(tmp[3] - (float)h3));
        }
        // ---- B fragments + MFMA ----
#pragma unroll
        for (int jt = 0; jt < 6; ++jt) {
            const float4 fb = *(const float4*)&base[brd[jt]];
            float tmp[4] = {fb.x, fb.y, fb.z, fb.w};
#pragma unroll
            for (int i = 0; i < 4; ++i) tmp[i] = okj[jt] ? tmp[i] : 0.f;
            f16 h0 = (f16)tmp[0], h1 = (f16)tmp[1], h2 = (f16)tmp[2], h3 = (f16)tmp[3];
            const FRAG_T bh = mkfrag(h0, h1, h2, h3);
            const FRAG_T bl = mkfrag((f16)(tmp[0] - (float)h0), (f16)(tmp[1] - (float)h1),
                                     (f16)(tmp[2] - (float)h2), (f16)(tmp[3] - (float)h3));
            if (jt < 5)  TRIPLE(jt, ah[0], al[0]);
            if (jt >= 1) TRIPLE(4 + jt, ah[1], al[1]);
        }
    }
#undef TRIPLE
#undef LOADK

    // ---- epilogue (wave-private): scatter band to LDS, coalesced stores ----
    f16* eb = (f16*)base;                  // [32 col][72 d] f16 = 4608 B
#pragma unroll
    for (int xt = 0; xt < 2; ++xt) {
#pragma unroll
        for (int p = 0; p < 5; ++p) {
            const int i = xt * 5 + p;
#pragma unroll
            for (int q = 0; q < 4; ++q) {
                const int m = kq * 4 + q;
                const int xl = xt * 16 + m;
                const int d = 16 * p + n - m;
                if ((unsigned)d < (unsigned)NDTOT)
                    eb[xl * DP + d] = (f16)acc[i][q];
            }
        }
    }
    // zero pad columns d=65..71 (32 x 7 = 224 entries)
#pragma unroll
    for (int i = 0; i < 4; ++i) {
        const int idx = l + 64 * i;
        if (idx < 224) {
            const int xl = idx / 7;
            eb[xl * DP + NDTOT + (idx - 7 * xl)] = (f16)0.f;
        }
    }
    // coalesced store: 32*72 f16 = 4608 B = 288 x 16B chunks
    uint4* dst = (uint4*)(ws + ((size_t)(b * HF + y) * WF + xs) * DP);
    const uint4* src = (const uint4*)eb;
#pragma unroll
    for (int i = 0; i < 5; ++i) {
        const int idx = l + 64 * i;
        if (idx < 288) dst[idx] = src[idx];
    }
}

// ---------------------------------------------------------------------------
// k2: 3x3 box-sum over ws + scale: out[b,d,y,x] = INV * sum_{3x3} ws[y+dy][x+dx][d]
// grid (16 x-tiles of 32, 32 y-tiles of 8, b); 256 thr.
// ---------------------------------------------------------------------------
__global__ __launch_bounds__(256)
void corr_box(const f16* __restrict__ ws, float* __restrict__ out) {
    const int xt = blockIdx.x;
    const int yt = blockIdx.y;
    const int b = blockIdx.z;
    const int t = threadIdx.x;
    const int x0b = xt * 32, y0 = yt * 8;

    __shared__ f16 S[10 * 34][DP];     // 48.96 KB

    for (int u = 0; u < 10; ++u) {
        const int yy = y0 - 1 + u;
        const bool yok = (unsigned)yy < (unsigned)HF;
        const f16* src = ws + ((size_t)(b * HF + yy) * WF + (x0b - 1)) * DP;
#pragma unroll
        for (int sub = 0; sub < 2; ++sub) {
            const int idx = sub * 256 + t;
            if (idx < 306) {
                const int v = idx / 9, dg = idx - v * 9;
                const int xx = x0b - 1 + v;
                f16x8 val;
#pragma unroll
                for (int jj = 0; jj < 8; ++jj) val[jj] = (f16)0.f;
                if (yok && (unsigned)xx < (unsigned)WF)
                    val = *(const f16x8*)(src + (size_t)v * DP + dg * 8);
                *(f16x8*)&S[u * 34 + v][dg * 8] = val;
            }
        }
    }
    __syncthreads();

    const int ly = t >> 5, lx = t & 31;
    const int yg = y0 + ly, xg = x0b + lx;
    float* o0 = out + (size_t)b * NDTOT * WH + (size_t)yg * WF + xg;

#pragma unroll 1
    for (int dg = 0; dg < 9; ++dg) {
        f16x8 s;
#pragma unroll
        for (int jj = 0; jj < 8; ++jj) s[jj] = (f16)0.f;
#pragma unroll
        for (int du = 0; du < 3; ++du)
#pragma unroll
            for (int dv = 0; dv < 3; ++dv)
                s += *(const f16x8*)&S[(ly + du) * 34 + (lx + dv)][dg * 8];
#pragma unroll
        for (int jj = 0; jj < 8; ++jj) {
            const int d = dg * 8 + jj;
            if (d < NDTOT) o0[(size_t)d * WH] = (float)s[jj] * INV;
        }
    }
}

// ---------------------------------------------------------------------------
// Emergency fallback (tiny ws): direct computation, slow but correct.
// ---------------------------------------------------------------------------
__global__ void corr_naive(const float* __restrict__ x0, const float* __restrict__ x1,
                           float* __restrict__ out) {
    const size_t total = (size_t)4 * NDTOT * WH;
    size_t idx = (size_t)blockIdx.x * blockDim.x + threadIdx.x;
    if (idx >= total) return;
    const int j = (int)(idx % WF);
    const int i = (int)((idx / WF) % HF);
    const int d = (int)((idx / WH) % NDTOT);
    const int b = (int)(idx / ((size_t)NDTOT * WH));
    const int disp = d - 32;
    float s = 0.f;
    for (int u = i - 1; u <= i + 1; ++u) {
        if (u < 0 || u >= HF) continue;
        for (int v = j - 1; v <= j + 1; ++v) {
            if (v < 0 || v >= WF) continue;
            const int v1c = v + disp;
            if (v1c < 0 || v1c >= WF) continue;
            const float* p0 = x0 + (size_t)b * CF * CH + (size_t)u * WF + v;
            const float* p1 = x1 + (size_t)b * CF * CH + (size_t)u * WF + v1c;
            for (int c = 0; c < CF; ++c)
                s += p0[(size_t)c * CH] * p1[(size_t)c * CH];
        }
    }
    out[idx] = s * INV;
}

// ---------------------------------------------------------------------------
extern "C" void kernel_launch(void* const* d_in, const int* in_sizes, int n_in,
                              void* d_out, int out_size, void* d_ws, size_t ws_size,
                              hipStream_t stream) {
    const float* x0 = (const float*)d_in[0];
    const float* x1 = (const float*)d_in[1];
    float* out = (float*)d_out;

    const size_t wsNeed = (size_t)4 * HF * WF * DP * sizeof(f16);  // 75.5 MB

    if (ws_size >= wsNeed) {
        f16* ws = (f16*)d_ws;
        corr_gram<<<dim3(4096), dim3(256), 0, stream>>>(x0, x1, ws);
        corr_box<<<dim3(16, 32, 4), dim3(256), 0, stream>>>(ws, out);
    } else {
        const size_t total = (size_t)4 * NDTOT * WH;
        const int blocks = (int)((total + 255) / 256);
        corr_naive<<<dim3(blocks), dim3(256), 0, stream>>>(x0, x1, out);
    }
}